// Round 4
// baseline (276.457 us; speedup 1.0000x reference)
//
#include <hip/hip_runtime.h>
#include <hip/hip_bf16.h>
#include <hip/hip_cooperative_groups.h>
#include <cstdint>

// CapsuleLinear: B=64, I=512, O=64, LIN=8, LOUT=16, 3 routing iterations.
// x: [64,512,8] f32, W: [64,512,16,8] f32, bias: [64,16] f32, out: [64,64,16] f32.
//
// ws layout: priors bf16 [b][i][o][v] (67,108,864 B), then 4 out buffers
// [64][64][16] f32 (4 x 262,144 B).
//
// Primary path:
//   k_priors (512 blocks): priors = einsum(W,x) -> bf16 ws; zeros out buffers.
//   k_fused  (cooperative, 256 blocks x 512 thr, 1 block/CU): each thread holds
//     its 16 priors rows (o=lane) in VGPRs; phase 0 sums them -> out0; then 3
//     routing iterations from registers with grid.sync between; then squash.
// Fallback (if cooperative launch is rejected): round-2 kernel sequence
//   k_sum0 + 3x k_route + k_fin (verified, ~100us).

typedef float float4v __attribute__((ext_vector_type(4)));
typedef float float2v __attribute__((ext_vector_type(2)));
typedef unsigned short ushort8 __attribute__((ext_vector_type(8)));

__device__ __forceinline__ float bf2f(unsigned short u) {
    union { unsigned int ui; float f; } cv;
    cv.ui = ((unsigned int)u) << 16;
    return cv.f;
}
__device__ __forceinline__ unsigned short f2bf(float f) {
    union { float f; unsigned int ui; } cv;
    cv.f = f;
    unsigned int u = cv.ui;
    unsigned int r = u + 0x7FFFu + ((u >> 16) & 1u);  // RNE
    return (unsigned short)(r >> 16);
}

// ---------------------------------------------------------------------------
// K1: priors[b,i,o,v] = sum_l W[o,i,v,l] * x[b,i,l], stored bf16.
// One block per i. Also zeros the 4 out buffers.
// ---------------------------------------------------------------------------
__global__ __launch_bounds__(256) void k_priors(const float* __restrict__ W,
                                                const float* __restrict__ x,
                                                unsigned short* __restrict__ priors,
                                                float* __restrict__ outb) {
    const int i = blockIdx.x;      // 0..511
    const int t = threadIdx.x;
    __shared__ float Wl[16 * 132]; // [o_local][v*8+l], row stride 132
    __shared__ float xl[512];      // [b][l]

    {
        int j = (blockIdx.x * 256 + t) * 2;
        *(float2v*)(outb + j) = (float2v){0.0f, 0.0f};
    }

    if (t < 128) {
        float4v v = *(const float4v*)(x + ((size_t)(t >> 1) * 512 + i) * 8 + (size_t)(t & 1) * 4);
        *(float4v*)(xl + t * 4) = v;
    }

    const int r  = t & 15;   // o within chunk
    const int bq = t >> 4;   // 0..15

    for (int oc = 0; oc < 4; ++oc) {
        __syncthreads();
        #pragma unroll
        for (int k = 0; k < 2; ++k) {
            int j  = t + k * 256;
            int ol = j >> 5;
            int r4 = j & 31;
            float4v v = *(const float4v*)(W + ((size_t)((oc * 16 + ol) * 512 + i)) * 128 + (size_t)r4 * 4);
            *(float4v*)(Wl + ol * 132 + r4 * 4) = v;
        }
        __syncthreads();

        float4v wreg[32];
        const float4v* wp = (const float4v*)(Wl + r * 132);
        #pragma unroll
        for (int j = 0; j < 32; ++j) wreg[j] = wp[j];

        const int o = oc * 16 + r;
        #pragma unroll
        for (int k = 0; k < 4; ++k) {
            const int b = bq + 16 * k;
            float4v xr0 = ((const float4v*)(xl + b * 8))[0];
            float4v xr1 = ((const float4v*)(xl + b * 8))[1];
            ushort8 u0, u1;
            #pragma unroll
            for (int v = 0; v < 16; ++v) {
                float s = 0.0f;
                #pragma unroll
                for (int l = 0; l < 8; ++l) {
                    int idx = v * 8 + l;
                    float wv = wreg[idx >> 2][idx & 3];
                    float xv = (l < 4) ? xr0[l & 3] : xr1[l & 3];
                    s = fmaf(wv, xv, s);
                }
                unsigned short hb = f2bf(s);
                if (v < 8) u0[v] = hb; else u1[v - 8] = hb;
            }
            unsigned short* dst = priors + ((size_t)(b * 512 + i) * 64 + o) * 16;
            *(ushort8*)(dst) = u0;
            *(ushort8*)(dst + 8) = u1;
        }
    }
}

// ---------------------------------------------------------------------------
// K_fused: sum0 + 3 routing iterations + squash (cooperative).
// Grid 256 = (b:64) x (q:4); block = 512 thr = 8 waves; wave w owns
// i in [q*128 + w*16, +16), lane == o. Priors fragment lives in VGPRs.
// ---------------------------------------------------------------------------
__global__ __launch_bounds__(512, 2) void k_fused(const unsigned short* __restrict__ priors,
                                                  float* __restrict__ outb,
                                                  const float* __restrict__ bias,
                                                  float* __restrict__ out) {
    const int b    = blockIdx.x >> 2;
    const int q    = blockIdx.x & 3;
    const int t    = threadIdx.x;
    const int w    = t >> 6;
    const int lane = t & 63;   // == o

    __shared__ float noutT[16 * 64];  // [v][o]
    __shared__ float red[7 * 1088];   // waves 1..7 partials, row pad 17

    // ---- phase 0: load priors fragment into regs + sum over i -> out0 ----
    ushort8 c0[16], c1[16];
    float acc[16];
    #pragma unroll
    for (int j = 0; j < 16; ++j) acc[j] = 0.0f;

    const unsigned short* basep = priors + (size_t)b * 524288
                                + (size_t)(q * 128 + w * 16) * 1024 + (size_t)lane * 16;
    #pragma unroll
    for (int k = 0; k < 16; ++k) {
        c0[k] = *(const ushort8*)(basep + (size_t)k * 1024);
        c1[k] = *(const ushort8*)(basep + (size_t)k * 1024 + 8);
        #pragma unroll
        for (int j = 0; j < 8; ++j) {
            acc[j]     += bf2f(c0[k][j]);
            acc[8 + j] += bf2f(c1[k][j]);
        }
    }
    if (w > 0) {
        #pragma unroll
        for (int j = 0; j < 16; ++j) red[(w - 1) * 1088 + lane * 17 + j] = acc[j];
    }
    __syncthreads();
    if (w == 0) {
        float* dst = outb + (size_t)b * 1024 + lane * 16;
        #pragma unroll
        for (int j = 0; j < 16; ++j) {
            float s = acc[j];
            #pragma unroll
            for (int ww = 0; ww < 7; ++ww) s += red[ww * 1088 + lane * 17 + j];
            atomicAdd(dst + j, s);
        }
    }

    cooperative_groups::this_grid().sync();

    // ---- phases 1..3: routing iterations from registers ----
    for (int r = 0; r < 3; ++r) {
        const float* oprev = outb + (size_t)r * 65536 + (size_t)b * 1024;
        float*       onext = outb + (size_t)(r + 1) * 65536 + (size_t)b * 1024;

        if (t < 64) {
            float vv[16]; float n2 = 0.0f;
            #pragma unroll
            for (int j = 0; j < 16; ++j) {
                vv[j] = __hip_atomic_load(oprev + t * 16 + j, __ATOMIC_RELAXED,
                                          __HIP_MEMORY_SCOPE_AGENT);
                n2 += vv[j] * vv[j];
            }
            float inv = 1.0f / fmaxf(sqrtf(n2), 1e-12f);
            #pragma unroll
            for (int j = 0; j < 16; ++j) noutT[j * 64 + t] = vv[j] * inv;
        }
        __syncthreads();

        float nr[16];
        #pragma unroll
        for (int j = 0; j < 16; ++j) nr[j] = noutT[j * 64 + lane];

        float a2[16];
        #pragma unroll
        for (int j = 0; j < 16; ++j) a2[j] = 0.0f;

        #pragma unroll
        for (int k = 0; k < 16; ++k) {
            float pf[16];
            #pragma unroll
            for (int j = 0; j < 8; ++j) { pf[j] = bf2f(c0[k][j]); pf[8 + j] = bf2f(c1[k][j]); }

            float logit = 0.0f;
            #pragma unroll
            for (int j = 0; j < 16; ++j) logit = fmaf(pf[j], nr[j], logit);

            float m = logit;
            #pragma unroll
            for (int d = 1; d < 64; d <<= 1) m = fmaxf(m, __shfl_xor(m, d));
            float e = __expf(logit - m);
            float s = e;
            #pragma unroll
            for (int d = 1; d < 64; d <<= 1) s += __shfl_xor(s, d);
            float p = e / s;

            #pragma unroll
            for (int j = 0; j < 16; ++j) a2[j] = fmaf(p, pf[j], a2[j]);
        }

        __syncthreads();  // ensure wave0's reads of red (prev phase) are done
        if (w > 0) {
            #pragma unroll
            for (int j = 0; j < 16; ++j) red[(w - 1) * 1088 + lane * 17 + j] = a2[j];
        }
        __syncthreads();
        if (w == 0) {
            #pragma unroll
            for (int j = 0; j < 16; ++j) {
                float s = a2[j];
                #pragma unroll
                for (int ww = 0; ww < 7; ++ww) s += red[ww * 1088 + lane * 17 + j];
                atomicAdd(onext + lane * 16 + j, s);
            }
        }
        cooperative_groups::this_grid().sync();
    }

    // ---- phase 4: squash + bias (one block per b suffices) ----
    if (q == 0 && t < 64) {
        const float* p = outb + (size_t)3 * 65536 + (size_t)b * 1024 + t * 16;
        float vv[16]; float n2 = 0.0f;
        #pragma unroll
        for (int j = 0; j < 16; ++j) {
            vv[j] = __hip_atomic_load(p + j, __ATOMIC_RELAXED, __HIP_MEMORY_SCOPE_AGENT);
            n2 += vv[j] * vv[j];
        }
        float n = sqrtf(n2);
        float sc = n / (1.0f + n2);
        float* qd = out + (size_t)b * 1024 + t * 16;
        #pragma unroll
        for (int j = 0; j < 16; ++j) qd[j] = vv[j] * sc + bias[t * 16 + j];
    }
}

// ------------------------- fallback path kernels ---------------------------
__global__ __launch_bounds__(256) void k_sum0(const unsigned short* __restrict__ priors,
                                              float* __restrict__ out0) {
    const int b    = blockIdx.x >> 3;
    const int ic   = blockIdx.x & 7;
    const int t    = threadIdx.x;
    const int slot = t & 127;
    const int io   = t >> 7;
    const int o    = slot >> 1;
    const int vh   = slot & 1;

    float acc[8];
    #pragma unroll
    for (int j = 0; j < 8; ++j) acc[j] = 0.0f;

    const unsigned short* base = priors + (size_t)b * 524288 + (size_t)o * 16 + vh * 8;
    for (int k = 0; k < 32; ++k) {
        const int i = ic * 64 + k * 2 + io;
        ushort8 u = *(const ushort8*)(base + (size_t)i * 1024);
        #pragma unroll
        for (int j = 0; j < 8; ++j) acc[j] += bf2f(u[j]);
    }

    __shared__ float red[8 * 128];
    if (io == 1) {
        #pragma unroll
        for (int j = 0; j < 8; ++j) red[j * 128 + slot] = acc[j];
    }
    __syncthreads();
    if (io == 0) {
        float* dst = out0 + (size_t)b * 1024 + o * 16 + vh * 8;
        #pragma unroll
        for (int j = 0; j < 8; ++j) atomicAdd(dst + j, acc[j] + red[j * 128 + slot]);
    }
}

__global__ __launch_bounds__(256) void k_route(const unsigned short* __restrict__ priors,
                                               const float* __restrict__ out_prev,
                                               float* __restrict__ out_next) {
    const int b    = blockIdx.x >> 3;
    const int h    = blockIdx.x & 7;
    const int t    = threadIdx.x;
    const int w    = t >> 6;
    const int lane = t & 63;

    __shared__ float noutT[16 * 64];
    __shared__ float accbuf[4 * 1088];

    if (t < 64) {
        const float* po = out_prev + (size_t)b * 1024 + t * 16;
        float vv[16]; float n2 = 0.0f;
        #pragma unroll
        for (int j = 0; j < 16; ++j) { vv[j] = po[j]; n2 += vv[j] * vv[j]; }
        float inv = 1.0f / fmaxf(sqrtf(n2), 1e-12f);
        #pragma unroll
        for (int j = 0; j < 16; ++j) noutT[j * 64 + t] = vv[j] * inv;
    }
    __syncthreads();

    float nr[16];
    #pragma unroll
    for (int j = 0; j < 16; ++j) nr[j] = noutT[j * 64 + lane];

    float acc[16];
    #pragma unroll
    for (int j = 0; j < 16; ++j) acc[j] = 0.0f;

    const size_t base = (size_t)b * 524288 + (size_t)lane * 16;
    for (int k = 0; k < 16; ++k) {
        const int i = h * 64 + w + 4 * k;
        const ushort8* pp = (const ushort8*)(priors + base + (size_t)i * 1024);
        ushort8 u0 = pp[0], u1 = pp[1];
        float pf[16];
        #pragma unroll
        for (int j = 0; j < 8; ++j) { pf[j] = bf2f(u0[j]); pf[8 + j] = bf2f(u1[j]); }

        float logit = 0.0f;
        #pragma unroll
        for (int j = 0; j < 16; ++j) logit = fmaf(pf[j], nr[j], logit);

        float m = logit;
        #pragma unroll
        for (int d = 1; d < 64; d <<= 1) m = fmaxf(m, __shfl_xor(m, d));
        float e = __expf(logit - m);
        float s = e;
        #pragma unroll
        for (int d = 1; d < 64; d <<= 1) s += __shfl_xor(s, d);
        float p = e / s;

        #pragma unroll
        for (int j = 0; j < 16; ++j) acc[j] = fmaf(p, pf[j], acc[j]);
    }

    #pragma unroll
    for (int j = 0; j < 16; ++j) accbuf[w * 1088 + lane * 17 + j] = acc[j];
    __syncthreads();

    for (int j = t; j < 1024; j += 256) {
        const int o = j >> 4, v = j & 15;
        const int idx = o * 17 + v;
        float s = accbuf[idx] + accbuf[1088 + idx] + accbuf[2176 + idx] + accbuf[3264 + idx];
        atomicAdd(out_next + (size_t)b * 1024 + j, s);
    }
}

__global__ __launch_bounds__(64) void k_fin(const float* __restrict__ outl,
                                            const float* __restrict__ bias,
                                            float* __restrict__ out) {
    const int b = blockIdx.x;
    const int o = threadIdx.x;
    const float* p = outl + (size_t)b * 1024 + o * 16;
    float vv[16]; float n2 = 0.0f;
    #pragma unroll
    for (int j = 0; j < 16; ++j) { vv[j] = p[j]; n2 += vv[j] * vv[j]; }
    float n = sqrtf(n2);
    float scale = n / (1.0f + n2);
    float* q = out + (size_t)b * 1024 + o * 16;
    #pragma unroll
    for (int j = 0; j < 16; ++j) q[j] = vv[j] * scale + bias[o * 16 + j];
}

extern "C" void kernel_launch(void* const* d_in, const int* in_sizes, int n_in,
                              void* d_out, int out_size, void* d_ws, size_t ws_size,
                              hipStream_t stream) {
    const float* x    = (const float*)d_in[0];   // [64,512,8]
    const float* W    = (const float*)d_in[1];   // [64,512,16,8]
    const float* bias = (const float*)d_in[2];   // [64,16]
    float* out = (float*)d_out;                  // [64,64,16]

    unsigned short* priors = (unsigned short*)d_ws;                       // 67,108,864 B
    float* outb = (float*)((char*)d_ws + (size_t)64 * 512 * 64 * 16 * 2); // 4 x 65536 f32

    k_priors<<<512, 256, 0, stream>>>(W, x, priors, outb);

    void* args[] = { (void*)&priors, (void*)&outb, (void*)&bias, (void*)&out };
    hipError_t err = hipLaunchCooperativeKernel((const void*)k_fused, dim3(256), dim3(512),
                                                args, 0, stream);
    if (err != hipSuccess) {
        (void)hipGetLastError();  // clear error state
        k_sum0  <<<512, 256, 0, stream>>>(priors, outb);
        k_route <<<512, 256, 0, stream>>>(priors, outb,               outb + 65536);
        k_route <<<512, 256, 0, stream>>>(priors, outb + 65536,       outb + 2 * 65536);
        k_route <<<512, 256, 0, stream>>>(priors, outb + 2 * 65536,   outb + 3 * 65536);
        k_fin   <<<64, 64, 0, stream>>>(outb + 3 * 65536, bias, out);
    }
}

// Round 5
// 105.975 us; speedup vs baseline: 2.6087x; 2.6087x over previous
//
#include <hip/hip_runtime.h>
#include <hip/hip_bf16.h>
#include <cstdint>

// CapsuleLinear: B=64, I=512, O=64, LIN=8, LOUT=16, 3 routing iterations.
// x: [64,512,8] f32, W: [64,512,16,8] f32, bias: [64,16] f32, out: [64,64,16] f32.
//
// ws layout:
//   priors bf16 [b][i][o][v]                       67,108,864 B
//   part[4] f32 [64 b][16 chunk][64 o * 16 v]      4 x 4,194,304 B
// Total: 83,886,080 B.
//
// Pipeline (no atomics, no zero-init, all writes are full overwrites):
//   k_priors (512 blocks): priors = einsum(W,x) -> bf16.
//   k_sum0   (1024 blocks): part0[b][ic] = sum of priors over ic's 32 i's.
//   k_route  (1024 blocks) x3: normalize(sum_ic part_r[b]) -> logits -> softmax
//            over o (lane==o, wave=64=O) -> weighted sum -> part_{r+1}[b][h].
//   k_fin    (64 blocks): squash(sum_ic part3[b]) + bias -> out.

typedef float float4v __attribute__((ext_vector_type(4)));
typedef unsigned short ushort8 __attribute__((ext_vector_type(8)));

__device__ __forceinline__ float bf2f(unsigned short u) {
    union { unsigned int ui; float f; } cv;
    cv.ui = ((unsigned int)u) << 16;
    return cv.f;
}
__device__ __forceinline__ unsigned short f2bf(float f) {
    union { float f; unsigned int ui; } cv;
    cv.f = f;
    unsigned int u = cv.ui;
    unsigned int r = u + 0x7FFFu + ((u >> 16) & 1u);  // RNE
    return (unsigned short)(r >> 16);
}

// ---------------------------------------------------------------------------
// K1: priors[b,i,o,v] = sum_l W[o,i,v,l] * x[b,i,l], stored bf16.
// One block per i. W[:,i,:,:] staged in 16-o chunks to LDS; each thread owns
// one o-row (128 W floats in regs) and 4 b's per chunk.
// ---------------------------------------------------------------------------
__global__ __launch_bounds__(256) void k_priors(const float* __restrict__ W,
                                                const float* __restrict__ x,
                                                unsigned short* __restrict__ priors) {
    const int i = blockIdx.x;      // 0..511
    const int t = threadIdx.x;
    __shared__ float Wl[16 * 132]; // [o_local][v*8+l], row stride 132
    __shared__ float xl[512];      // [b][l]

    if (t < 128) {
        float4v v = *(const float4v*)(x + ((size_t)(t >> 1) * 512 + i) * 8 + (size_t)(t & 1) * 4);
        *(float4v*)(xl + t * 4) = v;
    }

    const int r  = t & 15;   // o within chunk
    const int bq = t >> 4;   // 0..15

    for (int oc = 0; oc < 4; ++oc) {
        __syncthreads();
        #pragma unroll
        for (int k = 0; k < 2; ++k) {
            int j  = t + k * 256;
            int ol = j >> 5;
            int r4 = j & 31;
            float4v v = *(const float4v*)(W + ((size_t)((oc * 16 + ol) * 512 + i)) * 128 + (size_t)r4 * 4);
            *(float4v*)(Wl + ol * 132 + r4 * 4) = v;
        }
        __syncthreads();

        float4v wreg[32];
        const float4v* wp = (const float4v*)(Wl + r * 132);
        #pragma unroll
        for (int j = 0; j < 32; ++j) wreg[j] = wp[j];

        const int o = oc * 16 + r;
        #pragma unroll
        for (int k = 0; k < 4; ++k) {
            const int b = bq + 16 * k;
            float4v xr0 = ((const float4v*)(xl + b * 8))[0];
            float4v xr1 = ((const float4v*)(xl + b * 8))[1];
            ushort8 u0, u1;
            #pragma unroll
            for (int v = 0; v < 16; ++v) {
                float s = 0.0f;
                #pragma unroll
                for (int l = 0; l < 8; ++l) {
                    int idx = v * 8 + l;
                    float wv = wreg[idx >> 2][idx & 3];
                    float xv = (l < 4) ? xr0[l & 3] : xr1[l & 3];
                    s = fmaf(wv, xv, s);
                }
                unsigned short hb = f2bf(s);
                if (v < 8) u0[v] = hb; else u1[v - 8] = hb;
            }
            unsigned short* dst = priors + ((size_t)(b * 512 + i) * 64 + o) * 16;
            *(ushort8*)(dst) = u0;
            *(ushort8*)(dst + 8) = u1;
        }
    }
}

// ---------------------------------------------------------------------------
// K_sum0: part0[b][ic][o*16+v] = sum over 32 i's of priors[b,i,o,v].
// Grid 1024 = (b:64) x (ic:16). Non-atomic: each block owns its slot.
// ---------------------------------------------------------------------------
__global__ __launch_bounds__(256) void k_sum0(const unsigned short* __restrict__ priors,
                                              float* __restrict__ part0) {
    const int b    = blockIdx.x >> 4;
    const int ic   = blockIdx.x & 15;
    const int t    = threadIdx.x;
    const int slot = t & 127;   // (o, v-half)
    const int io   = t >> 7;    // i parity
    const int o    = slot >> 1;
    const int vh   = slot & 1;

    float acc[8];
    #pragma unroll
    for (int j = 0; j < 8; ++j) acc[j] = 0.0f;

    const unsigned short* base = priors + (size_t)b * 524288 + (size_t)o * 16 + vh * 8;
    #pragma unroll
    for (int k = 0; k < 16; ++k) {
        const int i = ic * 32 + k * 2 + io;
        ushort8 u = *(const ushort8*)(base + (size_t)i * 1024);
        #pragma unroll
        for (int j = 0; j < 8; ++j) acc[j] += bf2f(u[j]);
    }

    __shared__ float red[8 * 128];
    if (io == 1) {
        #pragma unroll
        for (int j = 0; j < 8; ++j) red[j * 128 + slot] = acc[j];
    }
    __syncthreads();
    if (io == 0) {
        float* dst = part0 + (size_t)b * 16384 + (size_t)ic * 1024 + o * 16 + vh * 8;
        #pragma unroll
        for (int j = 0; j < 8; ++j) dst[j] = acc[j] + red[j * 128 + slot];
    }
}

// ---------------------------------------------------------------------------
// K_route: one routing iteration.
//   out_prev[b,o,:] = sum_ic part_prev[b][ic]  (summed in normalize phase)
//   logits[b,o,i] = dot(priors[b,i,o,:], normalize(out_prev[b,o,:]))
//   probs = softmax over o; part_next[b][h] = sum_{i in h's 32} probs*priors
// Grid 1024 = (b:64) x (h:16); 4 waves; wave w owns i = h*32 + w + 4k.
// ---------------------------------------------------------------------------
__global__ __launch_bounds__(256) void k_route(const unsigned short* __restrict__ priors,
                                               const float* __restrict__ part_prev,
                                               float* __restrict__ part_next) {
    const int b    = blockIdx.x >> 4;
    const int h    = blockIdx.x & 15;
    const int t    = threadIdx.x;
    const int w    = t >> 6;
    const int lane = t & 63;   // == o

    __shared__ float noutT[16 * 64];   // [v][o]
    __shared__ float accbuf[4 * 1088]; // [wave][o*17+v]

    if (t < 64) {
        const float* pp = part_prev + (size_t)b * 16384 + t * 16;
        float4v s4[4];
        #pragma unroll
        for (int g = 0; g < 4; ++g) s4[g] = (float4v){0.f, 0.f, 0.f, 0.f};
        #pragma unroll
        for (int ic = 0; ic < 16; ++ic) {
            #pragma unroll
            for (int g = 0; g < 4; ++g)
                s4[g] += *(const float4v*)(pp + (size_t)ic * 1024 + g * 4);
        }
        float vv[16]; float n2 = 0.0f;
        #pragma unroll
        for (int j = 0; j < 16; ++j) { vv[j] = s4[j >> 2][j & 3]; n2 += vv[j] * vv[j]; }
        float inv = 1.0f / fmaxf(sqrtf(n2), 1e-12f);
        #pragma unroll
        for (int j = 0; j < 16; ++j) noutT[j * 64 + t] = vv[j] * inv;
    }
    __syncthreads();

    float nr[16];
    #pragma unroll
    for (int j = 0; j < 16; ++j) nr[j] = noutT[j * 64 + lane];

    float acc[16];
    #pragma unroll
    for (int j = 0; j < 16; ++j) acc[j] = 0.0f;

    const size_t base = (size_t)b * 524288 + (size_t)lane * 16;
    #pragma unroll
    for (int k = 0; k < 8; ++k) {
        const int i = h * 32 + w + 4 * k;
        const ushort8* pp = (const ushort8*)(priors + base + (size_t)i * 1024);
        ushort8 u0 = pp[0], u1 = pp[1];
        float pf[16];
        #pragma unroll
        for (int j = 0; j < 8; ++j) { pf[j] = bf2f(u0[j]); pf[8 + j] = bf2f(u1[j]); }

        float logit = 0.0f;
        #pragma unroll
        for (int j = 0; j < 16; ++j) logit = fmaf(pf[j], nr[j], logit);

        float m = logit;
        #pragma unroll
        for (int d = 1; d < 64; d <<= 1) m = fmaxf(m, __shfl_xor(m, d));
        float e = __expf(logit - m);
        float s = e;
        #pragma unroll
        for (int d = 1; d < 64; d <<= 1) s += __shfl_xor(s, d);
        float p = e / s;

        #pragma unroll
        for (int j = 0; j < 16; ++j) acc[j] = fmaf(p, pf[j], acc[j]);
    }

    #pragma unroll
    for (int j = 0; j < 16; ++j) accbuf[w * 1088 + lane * 17 + j] = acc[j];
    __syncthreads();

    float* dst = part_next + (size_t)b * 16384 + (size_t)h * 1024;
    for (int j = t; j < 1024; j += 256) {
        const int o = j >> 4, v = j & 15;
        const int idx = o * 17 + v;
        dst[j] = accbuf[idx] + accbuf[1088 + idx] + accbuf[2176 + idx] + accbuf[3264 + idx];
    }
}

// ---------------------------------------------------------------------------
// K_fin: out = squash(sum_ic part3[b][ic]) + bias
// ---------------------------------------------------------------------------
__global__ __launch_bounds__(64) void k_fin(const float* __restrict__ part3,
                                            const float* __restrict__ bias,
                                            float* __restrict__ out) {
    const int b = blockIdx.x;
    const int o = threadIdx.x;
    const float* pp = part3 + (size_t)b * 16384 + o * 16;
    float4v s4[4];
    #pragma unroll
    for (int g = 0; g < 4; ++g) s4[g] = (float4v){0.f, 0.f, 0.f, 0.f};
    #pragma unroll
    for (int ic = 0; ic < 16; ++ic) {
        #pragma unroll
        for (int g = 0; g < 4; ++g)
            s4[g] += *(const float4v*)(pp + (size_t)ic * 1024 + g * 4);
    }
    float vv[16]; float n2 = 0.0f;
    #pragma unroll
    for (int j = 0; j < 16; ++j) { vv[j] = s4[j >> 2][j & 3]; n2 += vv[j] * vv[j]; }
    float n = sqrtf(n2);
    float scale = n / (1.0f + n2);
    float* q = out + (size_t)b * 1024 + o * 16;
    #pragma unroll
    for (int j = 0; j < 16; ++j) q[j] = vv[j] * scale + bias[o * 16 + j];
}

extern "C" void kernel_launch(void* const* d_in, const int* in_sizes, int n_in,
                              void* d_out, int out_size, void* d_ws, size_t ws_size,
                              hipStream_t stream) {
    const float* x    = (const float*)d_in[0];   // [64,512,8]
    const float* W    = (const float*)d_in[1];   // [64,512,16,8]
    const float* bias = (const float*)d_in[2];   // [64,16]
    float* out = (float*)d_out;                  // [64,64,16]

    unsigned short* priors = (unsigned short*)d_ws;                        // 67,108,864 B
    float* part = (float*)((char*)d_ws + (size_t)64 * 512 * 64 * 16 * 2);  // 4 x 1,048,576 f32
    float* part0 = part;
    float* part1 = part + 1048576;
    float* part2 = part + 2 * 1048576;
    float* part3 = part + 3 * 1048576;

    k_priors<<<512, 256, 0, stream>>>(W, x, priors);
    k_sum0  <<<1024, 256, 0, stream>>>(priors, part0);
    k_route <<<1024, 256, 0, stream>>>(priors, part0, part1);
    k_route <<<1024, 256, 0, stream>>>(priors, part1, part2);
    k_route <<<1024, 256, 0, stream>>>(priors, part2, part3);
    k_fin   <<<64, 64, 0, stream>>>(part3, bias, out);
}